// Round 1
// baseline (451.447 us; speedup 1.0000x reference)
//
#include <hip/hip_runtime.h>
#include <hip/hip_bf16.h>

#define DD 128
#define HH 64
#define TT 12

// ---------------- Kernel T: transpose W1 [D,H]->W1t[H,D], W3 [D,D]->W3t[D,D]
__global__ void kT(const float* __restrict__ W1, const float* __restrict__ W3,
                   float* __restrict__ W1t, float* __restrict__ W3t) {
    int t = blockIdx.x * 256 + threadIdx.x;
    if (t < DD * HH) {
        int d = t / HH, j = t % HH;
        W1t[j * DD + d] = W1[t];
    }
    if (t < DD * DD) {
        int d = t / DD, j = t % DD;
        W3t[j * DD + d] = W3[t];
    }
}

// ---------------- Kernel A: per-pair attention score -> e[m] = exp(score[m])
// thread-per-row; x row in registers; W1t rows read uniformly (scalar path)
__global__ __launch_bounds__(256) void kScores(
    const float* __restrict__ feat, const int* __restrict__ fidx,
    const float* __restrict__ W1t, const float* __restrict__ b1,
    const float* __restrict__ W2, const float* __restrict__ b2,
    float* __restrict__ e, int M)
{
    int m = blockIdx.x * 256 + threadIdx.x;
    if (m >= M) return;
    const float* xr = feat + (size_t)fidx[m] * DD;
    float x[DD];
#pragma unroll
    for (int i = 0; i < DD / 4; ++i) {
        float4 v = *reinterpret_cast<const float4*>(xr + i * 4);
        x[i * 4 + 0] = v.x; x[i * 4 + 1] = v.y;
        x[i * 4 + 2] = v.z; x[i * 4 + 3] = v.w;
    }
    float score = b2[0];
    for (int j = 0; j < HH; ++j) {
        float h = b1[j];
        const float* wrow = W1t + j * DD;   // wave-uniform address stream
#pragma unroll
        for (int d = 0; d < DD; ++d) h = fmaf(x[d], wrow[d], h);
        score = fmaf(tanhf(h), W2[j], score);
    }
    e[m] = expf(score);   // max-subtraction dropped: mathematically identical alpha
}

// ---------------- Kernel B: per-segment softmax-weighted pooling
// one block (128 threads) per molecule b; sorted batch_idx -> binary search
__global__ __launch_bounds__(128) void kPool(
    const float* __restrict__ feat, const int* __restrict__ fidx,
    const int* __restrict__ bidx, const float* __restrict__ e,
    float* __restrict__ pooled, int M)
{
    int b = blockIdx.x;
    int d = threadIdx.x;
    // first m with bidx[m] >= b
    int lo = 0, hi = M;
    while (lo < hi) { int mid = (lo + hi) >> 1; if (bidx[mid] < b) lo = mid + 1; else hi = mid; }
    int start = lo;
    hi = M;
    while (lo < hi) { int mid = (lo + hi) >> 1; if (bidx[mid] < b + 1) lo = mid + 1; else hi = mid; }
    int end = lo;

    float acc = 0.f, denom = 0.f;
    for (int m = start; m < end; ++m) {
        float em = e[m];                       // uniform -> broadcast
        int idx = fidx[m];                     // uniform
        acc = fmaf(em, feat[(size_t)idx * DD + d], acc);  // coalesced row read
        denom += em;
    }
    pooled[(size_t)b * DD + d] = acc / (denom + 1e-16f);
}

// ---------------- Kernel C: logits = relu(pooled@W3+b3)@W4 + b4
// 64 molecules/block x 4 j-chunks; LDS reduce of partial logits
__global__ __launch_bounds__(256) void kPred(
    const float* __restrict__ pooled, const float* __restrict__ W3t,
    const float* __restrict__ b3, const float* __restrict__ W4,
    const float* __restrict__ b4, float* __restrict__ out, int B)
{
    __shared__ float red[4][64][TT];
    int lb = threadIdx.x & 63;
    int c  = threadIdx.x >> 6;       // wave id == chunk id (uniform per wave)
    int b  = blockIdx.x * 64 + lb;
    if (b >= B) return;
    float p[DD];
#pragma unroll
    for (int i = 0; i < DD / 4; ++i) {
        float4 v = *reinterpret_cast<const float4*>(pooled + (size_t)b * DD + i * 4);
        p[i * 4 + 0] = v.x; p[i * 4 + 1] = v.y;
        p[i * 4 + 2] = v.z; p[i * 4 + 3] = v.w;
    }
    float lg[TT];
#pragma unroll
    for (int t = 0; t < TT; ++t) lg[t] = 0.f;
    for (int jj = 0; jj < DD / 4; ++jj) {
        int j = c * (DD / 4) + jj;
        float h = b3[j];
        const float* wrow = W3t + j * DD;    // wave-uniform
#pragma unroll
        for (int d = 0; d < DD; ++d) h = fmaf(p[d], wrow[d], h);
        h = fmaxf(h, 0.f);
#pragma unroll
        for (int t = 0; t < TT; ++t) lg[t] = fmaf(h, W4[j * TT + t], lg[t]);
    }
#pragma unroll
    for (int t = 0; t < TT; ++t) red[c][lb][t] = lg[t];
    __syncthreads();
    if (c == 0) {
#pragma unroll
        for (int t = 0; t < TT; ++t)
            out[(size_t)b * TT + t] =
                b4[t] + red[0][lb][t] + red[1][lb][t] + red[2][lb][t] + red[3][lb][t];
    }
}

extern "C" void kernel_launch(void* const* d_in, const int* in_sizes, int n_in,
                              void* d_out, int out_size, void* d_ws, size_t ws_size,
                              hipStream_t stream) {
    const float* feat = (const float*)d_in[0];
    const int*   fidx = (const int*)d_in[1];
    const int*   bidx = (const int*)d_in[2];
    // d_in[3] = dim_size scalar (derived from out_size instead)
    const float* W1 = (const float*)d_in[4];
    const float* b1 = (const float*)d_in[5];
    const float* W2 = (const float*)d_in[6];
    const float* b2 = (const float*)d_in[7];
    const float* W3 = (const float*)d_in[8];
    const float* b3 = (const float*)d_in[9];
    const float* W4 = (const float*)d_in[10];
    const float* b4 = (const float*)d_in[11];

    int M = in_sizes[1];
    int B = out_size / TT;
    float* out = (float*)d_out;

    char* ws = (char*)d_ws;
    float* e      = (float*)ws;                                          // M floats
    float* pooled = (float*)(ws + (size_t)M * 4);                        // B*DD floats
    float* W1t    = (float*)(ws + (size_t)M * 4 + (size_t)B * DD * 4);   // HH*DD
    float* W3t    = W1t + DD * HH;                                       // DD*DD

    kT<<<64, 256, 0, stream>>>(W1, W3, W1t, W3t);
    kScores<<<(M + 255) / 256, 256, 0, stream>>>(feat, fidx, W1t, b1, W2, b2, e, M);
    kPool<<<B, 128, 0, stream>>>(feat, fidx, bidx, e, pooled, M);
    kPred<<<(B + 63) / 64, 256, 0, stream>>>(pooled, W3t, b3, W4, b4, out, B);
}

// Round 2
// 141.725 us; speedup vs baseline: 3.1854x; 3.1854x over previous
//
#include <hip/hip_runtime.h>
#include <hip/hip_bf16.h>
#include <math.h>

#define DD 128
#define HH 64
#define TT 12

typedef __bf16 bf16x8 __attribute__((ext_vector_type(8)));
typedef float  f32x4  __attribute__((ext_vector_type(4)));

// ---------------- Prep: pack W1 [D][H] fp32 into bf16 B-fragments for
// mfma_f32_16x16x32_bf16. frag f = kk*4+g (kk = k-chunk of 32, g = col group
// of 16). Element (lane l, e) = W1[32*kk + 8*(l>>4) + e][16*g + (l&15)].
// Stored so lane l reads W1f[f*512 + l*8 .. +7] as one 16B bf16x8.
__global__ void kPrep(const float* __restrict__ W1, __bf16* __restrict__ W1f) {
    int t = blockIdx.x * 256 + threadIdx.x;
    if (t >= 16 * 512) return;
    int f = t >> 9, l = (t >> 3) & 63, e = t & 7;
    int d = 32 * (f >> 2) + 8 * (l >> 4) + e;
    int j = 16 * (f & 3) + (l & 15);
    W1f[t] = (__bf16)W1[d * HH + j];
}

// ---------------- Kernel A: scores via MFMA. One wave per 16-row tile.
// A-frag (lane l, e) = x_row(l&15)[32*kk + 8*(l>>4) + e]  (fp32 gather -> bf16)
// C/D layout (m89-verified): col = l&15, row = 4*(l>>4) + reg.
__global__ __launch_bounds__(256) void kScores(
    const float* __restrict__ feat, const int* __restrict__ fidx,
    const __bf16* __restrict__ W1f, const float* __restrict__ b1,
    const float* __restrict__ W2, const float* __restrict__ b2,
    float* __restrict__ e, int M)
{
    int wave = threadIdx.x >> 6;
    int l = threadIdx.x & 63;
    int tile = blockIdx.x * 4 + wave;
    int m0 = tile * 16;
    if (m0 >= M) return;
    int r = l & 15, grp = l >> 4;
    int m = m0 + r;
    int idx = fidx[min(m, M - 1)];
    const float* xr = feat + (size_t)idx * DD + grp * 8;

    bf16x8 a[4];
#pragma unroll
    for (int kk = 0; kk < 4; ++kk) {
        float4 u = *reinterpret_cast<const float4*>(xr + kk * 32);
        float4 v = *reinterpret_cast<const float4*>(xr + kk * 32 + 4);
        bf16x8 t;
        t[0] = (__bf16)u.x; t[1] = (__bf16)u.y; t[2] = (__bf16)u.z; t[3] = (__bf16)u.w;
        t[4] = (__bf16)v.x; t[5] = (__bf16)v.y; t[6] = (__bf16)v.z; t[7] = (__bf16)v.w;
        a[kk] = t;
    }

    f32x4 acc[4] = {};
#pragma unroll
    for (int kk = 0; kk < 4; ++kk) {
#pragma unroll
        for (int g = 0; g < 4; ++g) {
            bf16x8 bfr = *reinterpret_cast<const bf16x8*>(W1f + (kk * 4 + g) * 512 + l * 8);
            acc[g] = __builtin_amdgcn_mfma_f32_16x16x32_bf16(a[kk], bfr, acc[g], 0, 0, 0);
        }
    }

    // epilogue: score[row] = b2 + sum_j tanh(h[row][j] + b1[j]) * W2[j]
    float part[4] = {0.f, 0.f, 0.f, 0.f};
#pragma unroll
    for (int g = 0; g < 4; ++g) {
        int j = 16 * g + r;          // col this lane holds in group g
        float b1j = b1[j], w2j = W2[j];
#pragma unroll
        for (int q = 0; q < 4; ++q)
            part[q] = fmaf(tanhf(acc[g][q] + b1j), w2j, part[q]);
    }
    // reduce across the 16 lanes sharing rows (xor bits 0..3)
#pragma unroll
    for (int q = 0; q < 4; ++q) {
#pragma unroll
        for (int off = 1; off < 16; off <<= 1)
            part[q] += __shfl_xor(part[q], off, 64);
    }
    if (r == 0) {
        float b2v = b2[0];
#pragma unroll
        for (int q = 0; q < 4; ++q) {
            int mm = m0 + grp * 4 + q;
            if (mm < M) e[mm] = expf(part[q] + b2v);  // max-subtraction dropped (scores bounded)
        }
    }
}

// ---------------- Kernel B: per-segment weighted pooling.
// 256 threads = 2 row-streams x 128 dims; unroll-2 -> 4 gather rows in flight.
__global__ __launch_bounds__(256) void kPool(
    const float* __restrict__ feat, const int* __restrict__ fidx,
    const int* __restrict__ bidx, const float* __restrict__ e,
    float* __restrict__ pooled, int M)
{
    __shared__ float sacc[256];
    __shared__ float sden[2];
    int b = blockIdx.x;
    int d = threadIdx.x & 127;
    int half = threadIdx.x >> 7;
    int lo = 0, hi = M;
    while (lo < hi) { int mid = (lo + hi) >> 1; if (bidx[mid] < b) lo = mid + 1; else hi = mid; }
    int start = lo;
    hi = M;
    while (lo < hi) { int mid = (lo + hi) >> 1; if (bidx[mid] <= b) lo = mid + 1; else hi = mid; }
    int end = lo;

    float acc = 0.f, den = 0.f;
    int mm = start + half;
    for (; mm + 2 < end; mm += 4) {
        float e0 = e[mm], e1 = e[mm + 2];
        int i0 = fidx[mm], i1 = fidx[mm + 2];
        acc = fmaf(e0, feat[(size_t)i0 * DD + d], acc);
        acc = fmaf(e1, feat[(size_t)i1 * DD + d], acc);
        den += e0 + e1;
    }
    for (; mm < end; mm += 2) {
        float e0 = e[mm]; int i0 = fidx[mm];
        acc = fmaf(e0, feat[(size_t)i0 * DD + d], acc);
        den += e0;
    }
    sacc[threadIdx.x] = acc;
    if (d == 0) sden[half] = den;
    __syncthreads();
    if (half == 0) {
        float tot = acc + sacc[128 + d];
        float dn = sden[0] + sden[1];
        pooled[(size_t)b * DD + d] = tot / (dn + 1e-16f);
    }
}

// ---------------- Kernel C: logits = relu(pooled@W3+b3)@W4 + b4
// 4 molecules per 128-thread block; W3 column j per thread, coalesced, reused x4.
__global__ __launch_bounds__(128) void kPred(
    const float* __restrict__ pooled, const float* __restrict__ W3,
    const float* __restrict__ b3, const float* __restrict__ W4,
    const float* __restrict__ b4, float* __restrict__ out, int B)
{
    __shared__ float psh[4][DD];
    __shared__ float hsh[4][DD];
    int j = threadIdx.x;
    int b0 = blockIdx.x * 4;
#pragma unroll
    for (int mm = 0; mm < 4; ++mm) {
        int b = b0 + mm;
        psh[mm][j] = (b < B) ? pooled[(size_t)b * DD + j] : 0.f;
    }
    __syncthreads();
    float bj = b3[j];
    float h[4];
#pragma unroll
    for (int mm = 0; mm < 4; ++mm) h[mm] = bj;
    for (int d = 0; d < DD; ++d) {
        float w = W3[d * DD + j];       // coalesced across j
#pragma unroll
        for (int mm = 0; mm < 4; ++mm) h[mm] = fmaf(psh[mm][d], w, h[mm]);
    }
#pragma unroll
    for (int mm = 0; mm < 4; ++mm) hsh[mm][j] = fmaxf(h[mm], 0.f);
    __syncthreads();
    if (j < 4 * TT) {
        int mm = j / TT, t = j % TT;
        int b = b0 + mm;
        if (b < B) {
            float lg = b4[t];
            for (int d = 0; d < DD; ++d) lg = fmaf(hsh[mm][d], W4[d * TT + t], lg);
            out[(size_t)b * TT + t] = lg;
        }
    }
}

extern "C" void kernel_launch(void* const* d_in, const int* in_sizes, int n_in,
                              void* d_out, int out_size, void* d_ws, size_t ws_size,
                              hipStream_t stream) {
    const float* feat = (const float*)d_in[0];
    const int*   fidx = (const int*)d_in[1];
    const int*   bidx = (const int*)d_in[2];
    const float* W1 = (const float*)d_in[4];
    const float* b1 = (const float*)d_in[5];
    const float* W2 = (const float*)d_in[6];
    const float* b2 = (const float*)d_in[7];
    const float* W3 = (const float*)d_in[8];
    const float* b3 = (const float*)d_in[9];
    const float* W4 = (const float*)d_in[10];
    const float* b4 = (const float*)d_in[11];

    int M = in_sizes[1];
    int B = out_size / TT;
    float* out = (float*)d_out;

    float* e      = (float*)d_ws;
    float* pooled = e + M;
    __bf16* W1f   = (__bf16*)(pooled + (size_t)B * DD);

    kPrep<<<32, 256, 0, stream>>>(W1, W1f);
    int tiles = (M + 15) / 16;
    kScores<<<(tiles + 3) / 4, 256, 0, stream>>>(feat, fidx, W1f, b1, W2, b2, e, M);
    kPool<<<B, 256, 0, stream>>>(feat, fidx, bidx, e, pooled, M);
    kPred<<<(B + 3) / 4, 128, 0, stream>>>(pooled, W3, b3, W4, b4, out, B);
}

// Round 3
// 93.685 us; speedup vs baseline: 4.8188x; 1.5128x over previous
//
#include <hip/hip_runtime.h>
#include <hip/hip_bf16.h>
#include <math.h>

#define DD 128
#define HH 64
#define TT 12

typedef __bf16 bf16x8 __attribute__((ext_vector_type(8)));
typedef float  f32x4  __attribute__((ext_vector_type(4)));

__device__ __forceinline__ float fast_tanh(float x) {
    float ex = __expf(2.f * x);                       // v_exp_f32 path
    return (ex - 1.f) * __builtin_amdgcn_rcpf(ex + 1.f);
}

// ---------------- Prep: pack W1 [D][H] fp32 into bf16 B-fragments for
// mfma_f32_16x16x32_bf16. frag f = kk*4+g. Element (lane l, e) =
// W1[32*kk + 8*(l>>4) + e][16*g + (l&15)]; lane l reads W1f[f*512+l*8] as bf16x8.
__global__ void kPrep(const float* __restrict__ W1, __bf16* __restrict__ W1f) {
    int t = blockIdx.x * 256 + threadIdx.x;
    if (t >= 16 * 512) return;
    int f = t >> 9, l = (t >> 3) & 63, e = t & 7;
    int d = 32 * (f >> 2) + 8 * (l >> 4) + e;
    int j = 16 * (f & 3) + (l & 15);
    W1f[t] = (__bf16)W1[d * HH + j];
}

// ---------------- Seg: segs[b] = first m with bidx[m] >= b; segs[B] = M.
__global__ void kSeg(const int* __restrict__ bidx, int* __restrict__ segs,
                     int M, int B) {
    int m = blockIdx.x * 256 + threadIdx.x;
    if (m >= M) return;
    int cur = bidx[m];
    int prev = (m == 0) ? -1 : bidx[m - 1];
    for (int b = prev + 1; b <= cur; ++b) segs[b] = m;
    if (m == M - 1)
        for (int b = cur + 1; b <= B; ++b) segs[b] = M;
}

// ---------------- Kernel A: scores via MFMA, one wave per 16-row tile.
__global__ __launch_bounds__(256) void kScores(
    const float* __restrict__ feat, const int* __restrict__ fidx,
    const __bf16* __restrict__ W1f, const float* __restrict__ b1,
    const float* __restrict__ W2, const float* __restrict__ b2,
    float* __restrict__ e, int M)
{
    int wave = threadIdx.x >> 6;
    int l = threadIdx.x & 63;
    int tile = blockIdx.x * 4 + wave;
    int m0 = tile * 16;
    if (m0 >= M) return;
    int r = l & 15, grp = l >> 4;
    int m = m0 + r;
    int idx = fidx[min(m, M - 1)];
    const float* xr = feat + (size_t)idx * DD + grp * 8;

    bf16x8 a[4];
#pragma unroll
    for (int kk = 0; kk < 4; ++kk) {
        float4 u = *reinterpret_cast<const float4*>(xr + kk * 32);
        float4 v = *reinterpret_cast<const float4*>(xr + kk * 32 + 4);
        bf16x8 t;
        t[0] = (__bf16)u.x; t[1] = (__bf16)u.y; t[2] = (__bf16)u.z; t[3] = (__bf16)u.w;
        t[4] = (__bf16)v.x; t[5] = (__bf16)v.y; t[6] = (__bf16)v.z; t[7] = (__bf16)v.w;
        a[kk] = t;
    }

    f32x4 acc[4] = {};
#pragma unroll
    for (int kk = 0; kk < 4; ++kk) {
#pragma unroll
        for (int g = 0; g < 4; ++g) {
            bf16x8 bfr = *reinterpret_cast<const bf16x8*>(W1f + (kk * 4 + g) * 512 + l * 8);
            acc[g] = __builtin_amdgcn_mfma_f32_16x16x32_bf16(a[kk], bfr, acc[g], 0, 0, 0);
        }
    }

    float part[4] = {0.f, 0.f, 0.f, 0.f};
#pragma unroll
    for (int g = 0; g < 4; ++g) {
        int j = 16 * g + r;
        float b1j = b1[j], w2j = W2[j];
#pragma unroll
        for (int q = 0; q < 4; ++q)
            part[q] = fmaf(fast_tanh(acc[g][q] + b1j), w2j, part[q]);
    }
#pragma unroll
    for (int q = 0; q < 4; ++q) {
#pragma unroll
        for (int off = 1; off < 16; off <<= 1)
            part[q] += __shfl_xor(part[q], off, 64);
    }
    if (r == 0) {
        float b2v = b2[0];
#pragma unroll
        for (int q = 0; q < 4; ++q) {
            int mm = m0 + grp * 4 + q;
            if (mm < M) e[mm] = __expf(part[q] + b2v);  // scores bounded; max-sub dropped
        }
    }
}

// ---------------- Kernel B: per-segment weighted pooling.
// Stage fidx/e for the segment chunk into LDS (coalesced), then gather with
// addresses known early -> many loads in flight.
__global__ __launch_bounds__(256) void kPool(
    const float* __restrict__ feat, const int* __restrict__ fidx,
    const float* __restrict__ e, const int* __restrict__ segs,
    float* __restrict__ pooled)
{
    __shared__ int   sidx[128];
    __shared__ float se[128];
    __shared__ float sacc[256];
    __shared__ float sden[2];
    int b = blockIdx.x;
    int start = segs[b], end = segs[b + 1];
    int d = threadIdx.x & 127;
    int half = threadIdx.x >> 7;

    float acc = 0.f, den = 0.f;
    for (int c = start; c < end; c += 128) {
        int n = min(128, end - c);
        __syncthreads();
        if (threadIdx.x < n) {
            sidx[threadIdx.x] = fidx[c + threadIdx.x];
            se[threadIdx.x]   = e[c + threadIdx.x];
        }
        __syncthreads();
#pragma unroll 4
        for (int rr = half; rr < n; rr += 2) {
            float ev = se[rr];
            acc = fmaf(ev, feat[(size_t)sidx[rr] * DD + d], acc);
            den += ev;
        }
    }
    sacc[threadIdx.x] = acc;
    if (d == 0) sden[half] = den;
    __syncthreads();
    if (half == 0) {
        float tot = acc + sacc[128 + d];
        float dn = sden[0] + sden[1];
        pooled[(size_t)b * DD + d] = tot / (dn + 1e-16f);
    }
}

// ---------------- Kernel C: logits = relu(pooled@W3+b3)@W4 + b4
__global__ __launch_bounds__(128) void kPred(
    const float* __restrict__ pooled, const float* __restrict__ W3,
    const float* __restrict__ b3, const float* __restrict__ W4,
    const float* __restrict__ b4, float* __restrict__ out, int B)
{
    __shared__ float psh[4][DD];
    __shared__ float hsh[4][DD];
    int j = threadIdx.x;
    int b0 = blockIdx.x * 4;
#pragma unroll
    for (int mm = 0; mm < 4; ++mm) {
        int b = b0 + mm;
        psh[mm][j] = (b < B) ? pooled[(size_t)b * DD + j] : 0.f;
    }
    __syncthreads();
    float bj = b3[j];
    float h[4];
#pragma unroll
    for (int mm = 0; mm < 4; ++mm) h[mm] = bj;
    for (int d = 0; d < DD; ++d) {
        float w = W3[d * DD + j];
#pragma unroll
        for (int mm = 0; mm < 4; ++mm) h[mm] = fmaf(psh[mm][d], w, h[mm]);
    }
#pragma unroll
    for (int mm = 0; mm < 4; ++mm) hsh[mm][j] = fmaxf(h[mm], 0.f);
    __syncthreads();
    if (j < 4 * TT) {
        int mm = j / TT, t = j % TT;
        int b = b0 + mm;
        if (b < B) {
            float lg = b4[t];
            for (int d = 0; d < DD; ++d) lg = fmaf(hsh[mm][d], W4[d * TT + t], lg);
            out[(size_t)b * TT + t] = lg;
        }
    }
}

extern "C" void kernel_launch(void* const* d_in, const int* in_sizes, int n_in,
                              void* d_out, int out_size, void* d_ws, size_t ws_size,
                              hipStream_t stream) {
    const float* feat = (const float*)d_in[0];
    const int*   fidx = (const int*)d_in[1];
    const int*   bidx = (const int*)d_in[2];
    const float* W1 = (const float*)d_in[4];
    const float* b1 = (const float*)d_in[5];
    const float* W2 = (const float*)d_in[6];
    const float* b2 = (const float*)d_in[7];
    const float* W3 = (const float*)d_in[8];
    const float* b3 = (const float*)d_in[9];
    const float* W4 = (const float*)d_in[10];
    const float* b4 = (const float*)d_in[11];

    int M = in_sizes[1];
    int B = out_size / TT;
    float* out = (float*)d_out;

    float*  e      = (float*)d_ws;                 // M
    float*  pooled = e + M;                        // B*DD
    __bf16* W1f    = (__bf16*)(pooled + (size_t)B * DD);  // 16*512 bf16
    int*    segs   = (int*)(W1f + 16 * 512);       // B+1

    kPrep<<<32, 256, 0, stream>>>(W1, W1f);
    kSeg<<<(M + 255) / 256, 256, 0, stream>>>(bidx, segs, M, B);
    int tiles = (M + 15) / 16;
    kScores<<<(tiles + 3) / 4, 256, 0, stream>>>(feat, fidx, W1f, b1, W2, b2, e, M);
    kPool<<<B, 256, 0, stream>>>(feat, fidx, e, segs, pooled);
    kPred<<<(B + 3) / 4, 128, 0, stream>>>(pooled, W3, b3, W4, b4, out, B);
}

// Round 4
// 73.303 us; speedup vs baseline: 6.1586x; 1.2781x over previous
//
#include <hip/hip_runtime.h>
#include <hip/hip_bf16.h>
#include <math.h>

#define DD 128
#define HH 64
#define TT 12

typedef __bf16 bf16x8 __attribute__((ext_vector_type(8)));
typedef float  f32x4  __attribute__((ext_vector_type(4)));

__device__ __forceinline__ float fast_tanh(float x) {
    float ex = __expf(2.f * x);
    return (ex - 1.f) * __builtin_amdgcn_rcpf(ex + 1.f);
}

// ---------------- Setup (fused): segment boundaries + W1 bf16 fragment pack.
// segs[b] = first m with bidx[m] >= b; segs[B] = M.
// W1f: frag f=kk*4+g, element (lane l, e) = W1[32*kk+8*(l>>4)+e][16*g+(l&15)],
// lane l reads W1f[f*512 + l*8] as one bf16x8.
__global__ void kSetup(const int* __restrict__ bidx, int* __restrict__ segs,
                       const float* __restrict__ W1, __bf16* __restrict__ W1f,
                       int M, int B) {
    int m = blockIdx.x * 256 + threadIdx.x;
    if (m < 16 * 512) {
        int f = m >> 9, l = (m >> 3) & 63, e = m & 7;
        int d = 32 * (f >> 2) + 8 * (l >> 4) + e;
        int j = 16 * (f & 3) + (l & 15);
        W1f[m] = (__bf16)W1[d * HH + j];
    }
    if (m >= M) return;
    int cur = bidx[m];
    int prev = (m == 0) ? -1 : bidx[m - 1];
    for (int b = prev + 1; b <= cur; ++b) segs[b] = m;
    if (m == M - 1)
        for (int b = cur + 1; b <= B; ++b) segs[b] = M;
}

// ---------------- Kernel A: DENSE unique-row scores -> uexp[n] = exp(score).
// Scores depend only on the row, so compute once per table row (N), not per
// pair (M = 6.25N). Sequential reads, no gather.
__global__ __launch_bounds__(256) void kUScore(
    const float* __restrict__ feat, const __bf16* __restrict__ W1f,
    const float* __restrict__ b1, const float* __restrict__ W2,
    const float* __restrict__ b2, float* __restrict__ uexp, int N)
{
    int wave = threadIdx.x >> 6;
    int l = threadIdx.x & 63;
    int m0 = (blockIdx.x * 4 + wave) * 16;
    if (m0 >= N) return;
    int r = l & 15, grp = l >> 4;
    const float* xr = feat + (size_t)min(m0 + r, N - 1) * DD + grp * 8;

    bf16x8 a[4];
#pragma unroll
    for (int kk = 0; kk < 4; ++kk) {
        float4 u = *reinterpret_cast<const float4*>(xr + kk * 32);
        float4 v = *reinterpret_cast<const float4*>(xr + kk * 32 + 4);
        bf16x8 t;
        t[0] = (__bf16)u.x; t[1] = (__bf16)u.y; t[2] = (__bf16)u.z; t[3] = (__bf16)u.w;
        t[4] = (__bf16)v.x; t[5] = (__bf16)v.y; t[6] = (__bf16)v.z; t[7] = (__bf16)v.w;
        a[kk] = t;
    }

    f32x4 acc[4] = {};
#pragma unroll
    for (int kk = 0; kk < 4; ++kk) {
#pragma unroll
        for (int g = 0; g < 4; ++g) {
            bf16x8 bfr = *reinterpret_cast<const bf16x8*>(W1f + (kk * 4 + g) * 512 + l * 8);
            acc[g] = __builtin_amdgcn_mfma_f32_16x16x32_bf16(a[kk], bfr, acc[g], 0, 0, 0);
        }
    }

    float part[4] = {0.f, 0.f, 0.f, 0.f};
#pragma unroll
    for (int g = 0; g < 4; ++g) {
        int j = 16 * g + r;
        float b1j = b1[j], w2j = W2[j];
#pragma unroll
        for (int q = 0; q < 4; ++q)
            part[q] = fmaf(fast_tanh(acc[g][q] + b1j), w2j, part[q]);
    }
#pragma unroll
    for (int q = 0; q < 4; ++q) {
#pragma unroll
        for (int off = 1; off < 16; off <<= 1)
            part[q] += __shfl_xor(part[q], off, 64);
    }
    if (r == 0) {
        float b2v = b2[0];
#pragma unroll
        for (int q = 0; q < 4; ++q) {
            int mm = m0 + grp * 4 + q;
            if (mm < N) uexp[mm] = __expf(part[q] + b2v);  // scores bounded; max-sub dropped
        }
    }
}

// ---------------- Kernel B: per-segment weighted pooling.
// Stage fidx + uexp[fidx] into LDS (uexp is 256 KB, L2-resident), then gather
// feature rows with addresses known early.
__global__ __launch_bounds__(256) void kPool(
    const float* __restrict__ feat, const int* __restrict__ fidx,
    const float* __restrict__ uexp, const int* __restrict__ segs,
    float* __restrict__ pooled)
{
    __shared__ int   sidx[128];
    __shared__ float se[128];
    __shared__ float sacc[256];
    __shared__ float sden[2];
    int b = blockIdx.x;
    int start = segs[b], end = segs[b + 1];
    int d = threadIdx.x & 127;
    int half = threadIdx.x >> 7;

    float acc = 0.f, den = 0.f;
    for (int c = start; c < end; c += 128) {
        int n = min(128, end - c);
        __syncthreads();
        if (threadIdx.x < n) {
            int fi = fidx[c + threadIdx.x];
            sidx[threadIdx.x] = fi;
            se[threadIdx.x]   = uexp[fi];
        }
        __syncthreads();
#pragma unroll 4
        for (int rr = half; rr < n; rr += 2) {
            float ev = se[rr];
            acc = fmaf(ev, feat[(size_t)sidx[rr] * DD + d], acc);
            den += ev;
        }
    }
    sacc[threadIdx.x] = acc;
    if (d == 0) sden[half] = den;
    __syncthreads();
    if (half == 0) {
        float tot = acc + sacc[128 + d];
        float dn = sden[0] + sden[1];
        pooled[(size_t)b * DD + d] = tot / (dn + 1e-16f);
    }
}

// ---------------- Kernel C: logits = relu(pooled@W3+b3)@W4 + b4
// 16 molecules/block: W3 read once per 16 rows; float4 LDS reads.
__global__ __launch_bounds__(128) void kPred(
    const float* __restrict__ pooled, const float* __restrict__ W3,
    const float* __restrict__ b3, const float* __restrict__ W4,
    const float* __restrict__ b4, float* __restrict__ out, int B)
{
    __shared__ float psh[16][DD];
    __shared__ float hsh[16][DD];
    int j = threadIdx.x;
    int b0 = blockIdx.x * 16;
#pragma unroll
    for (int mm = 0; mm < 16; ++mm) {
        int b = b0 + mm;
        psh[mm][j] = (b < B) ? pooled[(size_t)b * DD + j] : 0.f;
    }
    __syncthreads();
    float bj = b3[j];
    float h[16];
#pragma unroll
    for (int mm = 0; mm < 16; ++mm) h[mm] = bj;
    for (int d = 0; d < DD; d += 4) {
        float4 w4v = *reinterpret_cast<const float4*>(&W3[d * DD + j]);  // NOT contiguous; see below
        // W3[d*DD+j], W3[(d+1)*DD+j]... are strided by DD — load individually:
        (void)w4v;
        float w0 = W3[(d + 0) * DD + j];
        float w1 = W3[(d + 1) * DD + j];
        float w2 = W3[(d + 2) * DD + j];
        float w3v_ = W3[(d + 3) * DD + j];
#pragma unroll
        for (int mm = 0; mm < 16; ++mm) {
            float4 pv = *reinterpret_cast<const float4*>(&psh[mm][d]);
            h[mm] = fmaf(pv.x, w0, h[mm]);
            h[mm] = fmaf(pv.y, w1, h[mm]);
            h[mm] = fmaf(pv.z, w2, h[mm]);
            h[mm] = fmaf(pv.w, w3v_, h[mm]);
        }
    }
#pragma unroll
    for (int mm = 0; mm < 16; ++mm) hsh[mm][j] = fmaxf(h[mm], 0.f);
    __syncthreads();
    for (int p = j; p < 16 * TT; p += 128) {
        int mm = p / TT, t = p % TT;
        int b = b0 + mm;
        if (b < B) {
            float lg = b4[t];
            for (int d = 0; d < DD; ++d) lg = fmaf(hsh[mm][d], W4[d * TT + t], lg);
            out[(size_t)b * TT + t] = lg;
        }
    }
}

extern "C" void kernel_launch(void* const* d_in, const int* in_sizes, int n_in,
                              void* d_out, int out_size, void* d_ws, size_t ws_size,
                              hipStream_t stream) {
    const float* feat = (const float*)d_in[0];
    const int*   fidx = (const int*)d_in[1];
    const int*   bidx = (const int*)d_in[2];
    const float* W1 = (const float*)d_in[4];
    const float* b1 = (const float*)d_in[5];
    const float* W2 = (const float*)d_in[6];
    const float* b2 = (const float*)d_in[7];
    const float* W3 = (const float*)d_in[8];
    const float* b3 = (const float*)d_in[9];
    const float* W4 = (const float*)d_in[10];
    const float* b4 = (const float*)d_in[11];

    int N = in_sizes[0] / DD;      // unique substructure rows
    int M = in_sizes[1];
    int B = out_size / TT;
    float* out = (float*)d_out;

    float*  uexp   = (float*)d_ws;                        // N
    float*  pooled = uexp + N;                            // B*DD
    __bf16* W1f    = (__bf16*)(pooled + (size_t)B * DD);  // 16*512
    int*    segs   = (int*)(W1f + 16 * 512);              // B+1

    kSetup<<<(M + 255) / 256, 256, 0, stream>>>(bidx, segs, W1, W1f, M, B);
    int tiles = (N + 15) / 16;
    kUScore<<<(tiles + 3) / 4, 256, 0, stream>>>(feat, W1f, b1, W2, b2, uexp, N);
    kPool<<<B, 256, 0, stream>>>(feat, fidx, uexp, segs, pooled);
    kPred<<<(B + 15) / 16, 128, 0, stream>>>(pooled, W3, b3, W4, b4, out, B);
}